// Round 16
// baseline (487.860 us; speedup 1.0000x reference)
//
#include <hip/hip_runtime.h>
#include <hip/hip_bf16.h>
#include <math.h>

#define N_NODES 16384
#define E_EDGES 65536
#define ET (E_EDGES + N_NODES)   /* 81920 edges incl self loops */
#define IN_DIM 1536
#define HID 1024
#define XSTR 2048                /* fused xl|xr row stride */

typedef __attribute__((ext_vector_type(8))) short bf16x8;
typedef __attribute__((ext_vector_type(4))) float f32x4;

__device__ __forceinline__ unsigned short f2b(float f) {
  unsigned int u = __float_as_uint(f);
  u = (u + 0x7FFFu + ((u >> 16) & 1u)) >> 16;
  return (unsigned short)u;
}

__device__ __forceinline__ float b2f(unsigned short u) {
  return __uint_as_float((unsigned int)u << 16);
}

__device__ __forceinline__ void gload_lds16(const void* g, void* l) {
  __builtin_amdgcn_global_load_lds((const __attribute__((address_space(1))) void*)g,
                                   (__attribute__((address_space(3))) void*)l, 16, 0, 0);
}

__device__ __forceinline__ float gelu_exact(float y) {
  return 0.5f * y * (1.0f + erff(y * 0.70710678118654752f));
}

// ---------------------------------------------------------------------------
// fp32 -> bf16 convert (vectorized, streaming roofline)
__global__ void conv_bf16_kernel(const float* __restrict__ in, unsigned short* __restrict__ out, int n4) {
  int i = blockIdx.x * 256 + threadIdx.x;
  if (i < n4) {
    float4 v = ((const float4*)in)[i];
    ushort4 o;
    o.x = f2b(v.x); o.y = f2b(v.y); o.z = f2b(v.z); o.w = f2b(v.w);
    ((ushort4*)out)[i] = o;
  }
}

// ---------------------------------------------------------------------------
// ALL weight transposes fp32 [K][N] -> bf16 [N][K] in ONE launch.
__global__ void transpose_all_kernel(const float* __restrict__ W_in,
                                     const float* __restrict__ g1Wl, const float* __restrict__ g1Wr,
                                     const float* __restrict__ g2Wl, const float* __restrict__ g2Wr,
                                     const float* __restrict__ Ws1, const float* __restrict__ Ws2,
                                     unsigned short* __restrict__ WinT, unsigned short* __restrict__ g1WT,
                                     unsigned short* __restrict__ g2WT, unsigned short* __restrict__ Ws1T,
                                     unsigned short* __restrict__ Ws2T) {
  int bid = blockIdx.x;
  const float* src; unsigned short* dst; int K, N, tile;
  if (bid < 1536)      { src = W_in; dst = WinT;                          K = 1536; N = 1024; tile = bid; }
  else if (bid < 2560) { src = g1Wl; dst = g1WT;                         K = 1024; N = 1024; tile = bid - 1536; }
  else if (bid < 3584) { src = g1Wr; dst = g1WT + (size_t)1024 * 1024;   K = 1024; N = 1024; tile = bid - 2560; }
  else if (bid < 4608) { src = g2Wl; dst = g2WT;                         K = 1024; N = 1024; tile = bid - 3584; }
  else if (bid < 5632) { src = g2Wr; dst = g2WT + (size_t)1024 * 1024;   K = 1024; N = 1024; tile = bid - 4608; }
  else if (bid < 6144) { src = Ws1; dst = Ws1T;                          K = 1024; N = 512;  tile = bid - 5632; }
  else                 { src = Ws2; dst = Ws2T;                          K = 512;  N = 128;  tile = bid - 6144; }
  int nxt = N >> 5;
  int bx = (tile % nxt) * 32;
  int by = (tile / nxt) * 32;
  __shared__ float tilebuf[32][33];
  int tx = threadIdx.x, ty = threadIdx.y;
  #pragma unroll
  for (int i = 0; i < 32; i += 8)
    tilebuf[ty + i][tx] = src[(size_t)(by + ty + i) * N + bx + tx];
  __syncthreads();
  #pragma unroll
  for (int i = 0; i < 32; i += 8)
    dst[(size_t)(bx + ty + i) * K + by + tx] = f2b(tilebuf[tx][ty + i]);
}

// ---------------------------------------------------------------------------
// 8-PHASE GEMM (T2+T3+T4+T5, faithful phase body): C = A*Bt^T + bias.
// 256x256 tile, BK=64, 512 thr (8 waves, wr=w>>2 in {0,1}, wc=w&3 in {0..3}),
// per-wave 128x64 output (acc[8][4]).
// LDS [2dbuf][2 khalf][256 rows][64B] per operand = 128 KB. Per K-tile: 4
// phases (kh,mh), each = { 8 ds_read_b128 ; stage 1 half-tile of tile T+1 ;
// [vmcnt(4) @p1,p3] ; s_barrier ; lgkmcnt(0)+sched_barrier ; setprio(1) ;
// 16 MFMA ; setprio(0) ; s_barrier }.  Stage order [A-kh0,B-kh0,A-kh1,B-kh1];
// vmcnt(4) at p1 proves T's kh1 staged (4 newer = T+1's kh0); at p3 proves
// T+1's kh0 (4 newer = T+1's kh1). Last tile peeled (vmcnt(0) @p1).
// Swizzle: byte ^= ((row>>1)&3)<<4 within 64B rows, involution on both the
// pre-swizzled global source and the ds_read address (R8-verified, 0 confl).
// Dual bias like the 2-barrier kernel. WB: 0 fp32 only, 2 bf16 only.
#define VM4() asm volatile("s_waitcnt vmcnt(4)" ::: "memory")
#define VM0() asm volatile("s_waitcnt vmcnt(0)" ::: "memory")

#define STGA(kh, Tn)                                                           \
  do {                                                                         \
    const unsigned short* s_ = Ag + (size_t)(Tn) * 64 + (kh) * 32;             \
    gload_lds16(s_, Anxt + (kh) * 16384 + t * 16);                             \
    gload_lds16(s_ + rowK128, Anxt + (kh) * 16384 + 8192 + t * 16);            \
  } while (0)
#define STGB(kh, Tn)                                                           \
  do {                                                                         \
    const unsigned short* s_ = Bg + (size_t)(Tn) * 64 + (kh) * 32;             \
    gload_lds16(s_, Bnxt + (kh) * 16384 + t * 16);                             \
    gload_lds16(s_ + rowK128, Bnxt + (kh) * 16384 + 8192 + t * 16);            \
  } while (0)

#define PHASE(kh, mh, STG_STMT, VM_STMT)                                       \
  {                                                                            \
    const char* Ap_ = Acur + (kh) * 16384;                                     \
    const char* Bp_ = Bcur + (kh) * 16384;                                     \
    bf16x8 af_[4], bf_[4];                                                     \
    _Pragma("unroll") for (int m_ = 0; m_ < 4; m_++)                           \
      af_[m_] = *(const bf16x8*)(Ap_ + (ar + ((mh) * 4 + m_) * 16) * 64 + (kk2 ^ swA)); \
    _Pragma("unroll") for (int n_ = 0; n_ < 4; n_++)                           \
      bf_[n_] = *(const bf16x8*)(Bp_ + (br + n_ * 16) * 64 + (kk2 ^ swB));     \
    STG_STMT;                                                                  \
    VM_STMT;                                                                   \
    asm volatile("" ::: "memory");                                             \
    __builtin_amdgcn_s_barrier();                                              \
    asm volatile("s_waitcnt lgkmcnt(0)" ::: "memory");                         \
    __builtin_amdgcn_sched_barrier(0);                                         \
    __builtin_amdgcn_s_setprio(1);                                             \
    _Pragma("unroll") for (int m_ = 0; m_ < 4; m_++)                           \
      _Pragma("unroll") for (int n_ = 0; n_ < 4; n_++)                         \
        acc[(mh) * 4 + m_][n_] = __builtin_amdgcn_mfma_f32_16x16x32_bf16(      \
            af_[m_], bf_[n_], acc[(mh) * 4 + m_][n_], 0, 0, 0);                \
    __builtin_amdgcn_s_setprio(0);                                             \
    asm volatile("" ::: "memory");                                             \
    __builtin_amdgcn_s_barrier();                                              \
  }

template <int WB>
__global__ __launch_bounds__(512, 1)
void gemm8p_kernel(const unsigned short* __restrict__ A, const unsigned short* __restrict__ Bt,
                   const float* __restrict__ bias, const float* __restrict__ bias2, int nsplit,
                   float* __restrict__ C, unsigned short* __restrict__ Cb,
                   int M, int N, int K, int nx) {
  __shared__ char Abuf[2][32768];
  __shared__ char Bbuf[2][32768];
  const int t = threadIdx.x;
  const int l = t & 63;
  const int w = t >> 6;
  const int wr = w >> 2, wc = w & 3;

  // XCD-aware bijective remap (gridDim.x % 8 == 0 for all shapes here)
  const int nwg = gridDim.x;
  const int cpx = nwg >> 3;
  const int bid = blockIdx.x;
  const int tl = (bid & 7) * cpx + (bid >> 3);
  const int bm = (tl / nx) * 256;
  const int bn = (tl % nx) * 256;

  f32x4 acc[8][4];
  #pragma unroll
  for (int m = 0; m < 8; m++)
    #pragma unroll
    for (int n = 0; n < 4; n++) acc[m][n] = (f32x4){0.f, 0.f, 0.f, 0.f};

  // staging: thread t covers row srow = t>>2 (0..127) of a half (+128 for the
  // 2nd load), byte col (t&3)*16 pre-swizzled by ((row>>1)&3)<<4 (invariant
  // under row+128 and row+... since 64,128 are 0 mod 8).
  const int srow = t >> 2;
  const int scolb = ((t & 3) * 16) ^ (((srow >> 1) & 3) << 4);
  const unsigned short* Ag = A + (size_t)(bm + srow) * K + (scolb >> 1);
  const unsigned short* Bg = Bt + (size_t)(bn + srow) * K + (scolb >> 1);
  const size_t rowK128 = (size_t)128 * K;

  const int ar = wr * 128 + (l & 15);        // A tile row base (0..255)
  const int br = wc * 64 + (l & 15);         // B tile row base (0..255)
  const int kk2 = (l >> 4) * 16;             // k-frag byte offset within 64B row
  const int swA = ((ar >> 1) & 3) << 4;      // constant across m (m*16>>1 = 0 mod 4)
  const int swB = ((br >> 1) & 3) << 4;

  const int NT = K >> 6;                     // >= 16 for all uses

  // prologue: stage tile0 halves in order [A-kh0, B-kh0, A-kh1, B-kh1]
  gload_lds16(Ag, Abuf[0] + t * 16);
  gload_lds16(Ag + rowK128, Abuf[0] + 8192 + t * 16);
  gload_lds16(Bg, Bbuf[0] + t * 16);
  gload_lds16(Bg + rowK128, Bbuf[0] + 8192 + t * 16);
  gload_lds16(Ag + 32, Abuf[0] + 16384 + t * 16);
  gload_lds16(Ag + 32 + rowK128, Abuf[0] + 16384 + 8192 + t * 16);
  gload_lds16(Bg + 32, Bbuf[0] + 16384 + t * 16);
  gload_lds16(Bg + 32 + rowK128, Bbuf[0] + 16384 + 8192 + t * 16);
  VM4();                                     // A-kh0,B-kh0 of tile 0 resident
  asm volatile("" ::: "memory");
  __builtin_amdgcn_s_barrier();

  for (int T = 0; T < NT - 1; ++T) {
    const char* Acur = Abuf[T & 1];
    const char* Bcur = Bbuf[T & 1];
    char* Anxt = Abuf[(T + 1) & 1];
    char* Bnxt = Bbuf[(T + 1) & 1];
    PHASE(0, 0, STGA(0, T + 1), (void)0)
    PHASE(0, 1, STGB(0, T + 1), VM4())
    PHASE(1, 0, STGA(1, T + 1), (void)0)
    PHASE(1, 1, STGB(1, T + 1), VM4())
  }
  {
    const char* Acur = Abuf[(NT - 1) & 1];
    const char* Bcur = Bbuf[(NT - 1) & 1];
    PHASE(0, 0, (void)0, (void)0)
    PHASE(0, 1, (void)0, VM0())
    PHASE(1, 0, (void)0, (void)0)
    PHASE(1, 1, (void)0, (void)0)
  }

  const int crow0 = bm + wr * 128 + (l >> 4) * 4;
  const int ccol0 = bn + wc * 64 + (l & 15);
  #pragma unroll
  for (int m = 0; m < 8; m++) {
    #pragma unroll
    for (int n = 0; n < 4; n++) {
      int col = ccol0 + n * 16;
      float bv = (col < nsplit) ? bias[col] : bias2[col - nsplit];
      #pragma unroll
      for (int v = 0; v < 4; v++) {
        int row = crow0 + m * 16 + v;
        float x = acc[m][n][v] + bv;
        if (WB != 2) C[(size_t)row * N + col] = x;
        if (WB != 0) Cb[(size_t)row * N + col] = f2b(x);
      }
    }
  }
}

// ---------------------------------------------------------------------------
// bf16 MFMA GEMM (scorer path): C = A*Bt^T + bias; 256x128 tile, BK=64,
// 8 waves (4x2), single-buffer 2-barrier (proven 902 TF structure).
// ACT: 0 none, 1 silu.  WB: 0 fp32 only, 2 bf16 only.
template <int ACT, int WB>
__global__ __launch_bounds__(512)
void gemm_bf16_kernel(const unsigned short* __restrict__ A, const unsigned short* __restrict__ Bt,
                      const float* __restrict__ bias, const float* __restrict__ bias2, int nsplit,
                      float* __restrict__ C, unsigned short* __restrict__ Cb,
                      int M, int N, int K, int nx) {
  __shared__ unsigned short As[256 * 64];
  __shared__ unsigned short Bs[128 * 64];
  const int t = threadIdx.x;
  const int l = t & 63;
  const int w = t >> 6;            // 0..7
  const int wr = w >> 1, wc = w & 1;

  const int nwg = gridDim.x;
  const int bid = blockIdx.x;
  int tile = bid;
  if ((nwg & 7) == 0) {
    const int cpx = nwg >> 3;
    tile = (bid & 7) * cpx + (bid >> 3);
  }
  const int bm = (tile / nx) * 256;
  const int bn = (tile % nx) * 128;

  f32x4 acc[4][4];
  #pragma unroll
  for (int m = 0; m < 4; m++)
    #pragma unroll
    for (int n = 0; n < 4; n++) acc[m][n] = (f32x4){0.f, 0.f, 0.f, 0.f};

  const int srow = t >> 3;                                  // 0..63
  const int scolbsw = ((t & 7) * 16) ^ ((srow & 7) << 4);   // swizzled byte col
  const unsigned short* Ag = A + (size_t)(bm + srow) * K + (scolbsw >> 1);
  const unsigned short* Bg = Bt + (size_t)(bn + srow) * K + (scolbsw >> 1);

  const int ar = wr * 64 + (l & 15);        // 0..255
  const int br = wc * 64 + (l & 15);        // 0..127
  const int kk2 = (l >> 4) * 16;            // k-fragment byte offset
  const int swA = (ar & 7) << 4;
  const int swB = (br & 7) << 4;
  const char* Asb = (const char*)As;
  const char* Bsb = (const char*)Bs;

  for (int k0 = 0; k0 < K; k0 += 64) {
    #pragma unroll
    for (int i = 0; i < 4; i++)
      gload_lds16(Ag + (size_t)i * 64 * K + k0, (char*)As + t * 16 + i * 8192);
    #pragma unroll
    for (int i = 0; i < 2; i++)
      gload_lds16(Bg + (size_t)i * 64 * K + k0, (char*)Bs + t * 16 + i * 8192);
    __syncthreads();
    bf16x8 af[4], bfr[4];
    #pragma unroll
    for (int kh = 0; kh < 2; kh++) {
      const int kb = kk2 + kh * 64;
      #pragma unroll
      for (int m = 0; m < 4; m++)
        af[m] = *(const bf16x8*)(Asb + (ar + m * 16) * 128 + (kb ^ swA));
      #pragma unroll
      for (int n = 0; n < 4; n++)
        bfr[n] = *(const bf16x8*)(Bsb + (br + n * 16) * 128 + (kb ^ swB));
      #pragma unroll
      for (int m = 0; m < 4; m++)
        #pragma unroll
        for (int n = 0; n < 4; n++)
          acc[m][n] = __builtin_amdgcn_mfma_f32_16x16x32_bf16(af[m], bfr[n], acc[m][n], 0, 0, 0);
    }
    __syncthreads();
  }

  const int crow0 = bm + wr * 64 + (l >> 4) * 4;
  const int ccol0 = bn + wc * 64 + (l & 15);
  #pragma unroll
  for (int m = 0; m < 4; m++) {
    #pragma unroll
    for (int n = 0; n < 4; n++) {
      int col = ccol0 + n * 16;
      float bv = (col < nsplit) ? bias[col] : bias2[col - nsplit];
      #pragma unroll
      for (int v = 0; v < 4; v++) {
        int row = crow0 + m * 16 + v;
        float x = acc[m][n][v] + bv;
        if (ACT == 1) x = x / (1.0f + expf(-x));   // silu
        if (WB != 2) C[(size_t)row * N + col] = x;
        if (WB != 0) Cb[(size_t)row * N + col] = f2b(x);
      }
    }
  }
}

// ---------------------------------------------------------------------------
// layernorm + exact gelu from bf16 input; writes bf16 only.
__global__ __launch_bounds__(256)
void ln_gelu_kernel(const unsigned short* __restrict__ cb, const float* __restrict__ g,
                    const float* __restrict__ b, unsigned short* __restrict__ hb) {
  int row = blockIdx.x;
  int t = threadIdx.x;
  int c0 = t * 4;
  ushort4 u = *(const ushort4*)(cb + (size_t)row * HID + c0);
  float v0 = b2f(u.x), v1 = b2f(u.y), v2 = b2f(u.z), v3 = b2f(u.w);
  float s = v0 + v1 + v2 + v3;
  float q = v0 * v0 + v1 * v1 + v2 * v2 + v3 * v3;
  #pragma unroll
  for (int off = 32; off; off >>= 1) {
    s += __shfl_xor(s, off);
    q += __shfl_xor(q, off);
  }
  __shared__ float rs[4], rq[4];
  int wv = t >> 6, l = t & 63;
  if (l == 0) { rs[wv] = s; rq[wv] = q; }
  __syncthreads();
  s = rs[0] + rs[1] + rs[2] + rs[3];
  q = rq[0] + rq[1] + rq[2] + rq[3];
  float mu = s * (1.0f / HID);
  float var = q * (1.0f / HID) - mu * mu;
  float rstd = rsqrtf(var + 1e-5f);
  const float4 gv = *(const float4*)(g + c0);
  const float4 bv = *(const float4*)(b + c0);
  ushort4 ob;
  ob.x = f2b(gelu_exact((v0 - mu) * rstd * gv.x + bv.x));
  ob.y = f2b(gelu_exact((v1 - mu) * rstd * gv.y + bv.y));
  ob.z = f2b(gelu_exact((v2 - mu) * rstd * gv.z + bv.z));
  ob.w = f2b(gelu_exact((v3 - mu) * rstd * gv.w + bv.w));
  *(ushort4*)(hb + (size_t)row * HID + c0) = ob;
}

// ---------------------------------------------------------------------------
// edge list build (+ self loops) and dst-degree histogram
__global__ void build_edges_kernel(const int* __restrict__ ei, int* __restrict__ srcA,
                                   int* __restrict__ dstA, int* __restrict__ deg) {
  int i = blockIdx.x * 256 + threadIdx.x;
  if (i >= ET) return;
  int s, d;
  if (i < E_EDGES) { s = ei[i]; d = ei[E_EDGES + i]; }
  else             { s = i - E_EDGES; d = s; }
  srcA[i] = s;
  dstA[i] = d;
  atomicAdd(&deg[d], 1);
}

// exclusive scan of 16384 degrees, single block of 1024 threads
__global__ __launch_bounds__(1024)
void scan16k_kernel(const int* __restrict__ deg, int* __restrict__ rowstart) {
  __shared__ int s[1024];
  int t = threadIdx.x;
  int local[16];
  int sum = 0;
  #pragma unroll
  for (int i = 0; i < 16; i++) { local[i] = deg[t * 16 + i]; sum += local[i]; }
  s[t] = sum;
  __syncthreads();
  for (int off = 1; off < 1024; off <<= 1) {
    int v = (t >= off) ? s[t - off] : 0;
    __syncthreads();
    s[t] += v;
    __syncthreads();
  }
  int run = s[t] - sum;
  #pragma unroll
  for (int i = 0; i < 16; i++) { rowstart[t * 16 + i] = run; run += local[i]; }
  if (t == 1023) rowstart[16384] = run;
}

// scatter edges into CSR slots; store src per CSR position
__global__ void scatter_edges_kernel(const int* __restrict__ srcA, const int* __restrict__ dstA,
                                     const int* __restrict__ rowstart, int* __restrict__ cursor,
                                     int* __restrict__ src_csr) {
  int i = blockIdx.x * 256 + threadIdx.x;
  if (i >= ET) return;
  int d = dstA[i];
  int pos = atomicAdd(&cursor[d], 1);
  src_csr[rowstart[d] + pos] = srcA[i];
}

// ---------------------------------------------------------------------------
// FUSED GAT layer tail, WAVE-PER-NODE (proven 70us config): edge logits +
// online softmax (defer-max) + aggregate + bias + LayerNorm + gelu + residual.
// bf16 residual chain; WRITE_H=1 additionally writes the final fp32 h.
template <int WRITE_H>
__global__ __launch_bounds__(256)
void gat_fused_kernel(const unsigned short* __restrict__ xe, const float* __restrict__ att,
                      const int* __restrict__ src_csr, const int* __restrict__ rowstart,
                      const float* __restrict__ bo, const float* __restrict__ lng,
                      const float* __restrict__ lnb, float* __restrict__ h,
                      unsigned short* __restrict__ hb) {
  const int l = threadIdx.x & 63;
  const int nid = blockIdx.x * 4 + (threadIdx.x >> 6);
  const int beg = rowstart[nid], end = rowstart[nid + 1];
  const int cb = l * 16;      // channel base for this lane

  float xrf[16], attf[16];
  {
    const unsigned short* xrd = xe + (size_t)nid * XSTR + 1024 + cb;
    bf16x8 r0 = *(const bf16x8*)xrd;
    bf16x8 r1 = *(const bf16x8*)(xrd + 8);
    #pragma unroll
    for (int j = 0; j < 8; j++) {
      xrf[j] = b2f((unsigned short)r0[j]);
      xrf[j + 8] = b2f((unsigned short)r1[j]);
    }
    #pragma unroll
    for (int j = 0; j < 4; j++) {
      float4 a = *(const float4*)(att + cb + j * 4);
      attf[j * 4] = a.x; attf[j * 4 + 1] = a.y;
      attf[j * 4 + 2] = a.z; attf[j * 4 + 3] = a.w;
    }
  }

  float m = -1e30f, den = 0.f;
  float acc[16];
  #pragma unroll
  for (int j = 0; j < 16; j++) acc[j] = 0.f;

  bf16x8 xa0, xa1, xb0, xb1;
  if (beg < end) {
    const unsigned short* p = xe + (size_t)src_csr[beg] * XSTR + cb;
    xa0 = *(const bf16x8*)p;
    xa1 = *(const bf16x8*)(p + 8);
  }
  if (beg + 1 < end) {
    const unsigned short* p = xe + (size_t)src_csr[beg + 1] * XSTR + cb;
    xb0 = *(const bf16x8*)p;
    xb1 = *(const bf16x8*)(p + 8);
  }
  for (int e = beg; e < end; ++e) {
    bf16x8 c0 = xa0, c1 = xa1;
    xa0 = xb0; xa1 = xb1;
    if (e + 2 < end) {
      const unsigned short* p = xe + (size_t)src_csr[e + 2] * XSTR + cb;
      xb0 = *(const bf16x8*)p;
      xb1 = *(const bf16x8*)(p + 8);
    }
    float xf[16];
    #pragma unroll
    for (int j = 0; j < 8; j++) {
      xf[j] = b2f((unsigned short)c0[j]);
      xf[j + 8] = b2f((unsigned short)c1[j]);
    }
    float lg = 0.f;
    #pragma unroll
    for (int j = 0; j < 16; j++) {
      float u = xf[j] + xrf[j];
      u = fmaxf(u, 0.2f * u);            // leaky_relu (slope<1)
      lg = fmaf(u, attf[j], lg);
    }
    lg += __shfl_xor(lg, 1);
    lg += __shfl_xor(lg, 2);
    lg += __shfl_xor(lg, 4);             // lg = logit of head l>>3
    if (__all(lg <= m + 8.f)) {
      float wgt = expf(lg - m);
      den += wgt;
      #pragma unroll
      for (int j = 0; j < 16; j++) acc[j] = fmaf(wgt, xf[j], acc[j]);
    } else {
      float nm = fmaxf(m, lg);
      float sc = expf(m - nm);           // first edge: exp(-1e30) == 0
      float wgt = expf(lg - nm);
      den = den * sc + wgt;
      #pragma unroll
      for (int j = 0; j < 16; j++) acc[j] = fmaf(wgt, xf[j], acc[j] * sc);
      m = nm;
    }
  }

  float inv = 1.0f / den;
  float v[16];
  #pragma unroll
  for (int j = 0; j < 4; j++) {
    float4 b = *(const float4*)(bo + cb + j * 4);
    v[j * 4] = acc[j * 4] * inv + b.x;
    v[j * 4 + 1] = acc[j * 4 + 1] * inv + b.y;
    v[j * 4 + 2] = acc[j * 4 + 2] * inv + b.z;
    v[j * 4 + 3] = acc[j * 4 + 3] * inv + b.w;
  }
  float s = 0.f, q = 0.f;
  #pragma unroll
  for (int j = 0; j < 16; j++) { s += v[j]; q += v[j] * v[j]; }
  #pragma unroll
  for (int off = 32; off; off >>= 1) {
    s += __shfl_xor(s, off);
    q += __shfl_xor(q, off);
  }
  float mu = s * (1.0f / HID);
  float var = q * (1.0f / HID) - mu * mu;
  float rstd = rsqrtf(var + 1e-5f);

  float* hr = h + (size_t)nid * HID + cb;
  unsigned short* hbr = hb + (size_t)nid * HID + cb;
  #pragma unroll
  for (int j = 0; j < 4; j++) {
    float4 gv = *(const float4*)(lng + cb + j * 4);
    float4 bb = *(const float4*)(lnb + cb + j * 4);
    ushort4 hu = *(const ushort4*)(hbr + j * 4);   // bf16 residual in
    float o0 = b2f(hu.x) + gelu_exact((v[j * 4] - mu) * rstd * gv.x + bb.x);
    float o1 = b2f(hu.y) + gelu_exact((v[j * 4 + 1] - mu) * rstd * gv.y + bb.y);
    float o2 = b2f(hu.z) + gelu_exact((v[j * 4 + 2] - mu) * rstd * gv.z + bb.z);
    float o3 = b2f(hu.w) + gelu_exact((v[j * 4 + 3] - mu) * rstd * gv.w + bb.w);
    if (WRITE_H) *(float4*)(hr + j * 4) = (float4){o0, o1, o2, o3};
    ushort4 ob;
    ob.x = f2b(o0); ob.y = f2b(o1); ob.z = f2b(o2); ob.w = f2b(o3);
    *(ushort4*)(hbr + j * 4) = ob;
  }
}

// final scorer dot: scores[n] = dot(s2[n][0:128], Ws3) + bs3
__global__ __launch_bounds__(256)
void score_kernel(const float* __restrict__ s2, const float* __restrict__ Ws3,
                  const float* __restrict__ bs3, float* __restrict__ out) {
  int nid = blockIdx.x * 4 + (threadIdx.x >> 6);
  int l = threadIdx.x & 63;
  const float* r = s2 + (size_t)nid * 128;
  float a = r[l] * Ws3[l] + r[l + 64] * Ws3[l + 64];
  #pragma unroll
  for (int off = 32; off; off >>= 1) a += __shfl_xor(a, off);
  if (l == 0) out[nid] = a + bs3[0];
}

// ---------------------------------------------------------------------------
extern "C" void kernel_launch(void* const* d_in, const int* in_sizes, int n_in,
                              void* d_out, int out_size, void* d_ws, size_t ws_size,
                              hipStream_t stream) {
  const float* x    = (const float*)d_in[0];
  const int*   ei   = (const int*)  d_in[1];
  const float* W_in = (const float*)d_in[2];
  const float* b_in = (const float*)d_in[3];
  const float* ln1g = (const float*)d_in[4];
  const float* ln1b = (const float*)d_in[5];
  const float* g1Wl = (const float*)d_in[6];
  const float* g1bl = (const float*)d_in[7];
  const float* g1Wr = (const float*)d_in[8];
  const float* g1br = (const float*)d_in[9];
  const float* g1att= (const float*)d_in[10];
  const float* g1bo = (const float*)d_in[11];
  const float* ln2g = (const float*)d_in[12];
  const float* ln2b = (const float*)d_in[13];
  const float* g2Wl = (const float*)d_in[14];
  const float* g2bl = (const float*)d_in[15];
  const float* g2Wr = (const float*)d_in[16];
  const float* g2br = (const float*)d_in[17];
  const float* g2att= (const float*)d_in[18];
  const float* g2bo = (const float*)d_in[19];
  const float* ln3g = (const float*)d_in[20];
  const float* ln3b = (const float*)d_in[21];
  const float* Ws1  = (const float*)d_in[22];
  const float* bs1  = (const float*)d_in[23];
  const float* Ws2  = (const float*)d_in[24];
  const float* bs2  = (const float*)d_in[25];
  const float* Ws3  = (const float*)d_in[26];
  const float* bs3  = (const float*)d_in[27];

  float* scores = (float*)d_out;
  float* h      = (float*)d_out + N_NODES;  // [N][1024] fp32, second output

  char* wsp = (char*)d_ws;
  size_t off = 0;
  auto alloc = [&](size_t bytes) -> char* {
    char* p = wsp + off;
    off += (bytes + 255) & ~(size_t)255;
    return p;
  };
  unsigned short* xb    = (unsigned short*)alloc((size_t)N_NODES * IN_DIM * 2);
  unsigned short* WinT  = (unsigned short*)alloc((size_t)HID * IN_DIM * 2);
  unsigned short* g1WT  = (unsigned short*)alloc((size_t)XSTR * HID * 2);  // [Wl;Wr]^T
  unsigned short* g2WT  = (unsigned short*)alloc((size_t)XSTR * HID * 2);
  unsigned short* Ws1T  = (unsigned short*)alloc((size_t)512 * HID * 2);
  unsigned short* Ws2T  = (unsigned short*)alloc((size_t)128 * 512 * 2);
  unsigned short* hb    = (unsigned short*)alloc((size_t)N_NODES * HID * 2);
  unsigned short* s1b   = (unsigned short*)alloc((size_t)N_NODES * 512 * 2);
  unsigned short* xe    = (unsigned short*)alloc((size_t)N_NODES * XSTR * 2); // fused xl|xr
  float* C      = (float*)alloc((size_t)N_NODES * HID * 4);
  int* srcA     = (int*)alloc((size_t)ET * 4);
  int* dstA     = (int*)alloc((size_t)ET * 4);
  int* deg      = (int*)alloc(65536);
  int* cursor   = (int*)alloc(65536);
  int* rowstart = (int*)alloc(65544);
  int* src_csr  = (int*)alloc((size_t)ET * 4);
  unsigned short* cbp = (unsigned short*)C;   // bf16 proj output aliases C (used before scorer)

  // --- weight/input conversions (batched) ---
  conv_bf16_kernel<<<(N_NODES * IN_DIM / 4 + 255) / 256, 256, 0, stream>>>(x, xb, N_NODES * IN_DIM / 4);
  transpose_all_kernel<<<6208, dim3(32, 8), 0, stream>>>(W_in, g1Wl, g1Wr, g2Wl, g2Wr, Ws1, Ws2,
                                                         WinT, g1WT, g2WT, Ws1T, Ws2T);

  // --- CSR build (shared by both GAT layers) ---
  hipMemsetAsync(deg, 0, 131072, stream);  // deg + cursor (contiguous)
  build_edges_kernel<<<ET / 256, 256, 0, stream>>>(ei, srcA, dstA, deg);
  scan16k_kernel<<<1, 1024, 0, stream>>>(deg, rowstart);
  scatter_edges_kernel<<<ET / 256, 256, 0, stream>>>(srcA, dstA, rowstart, cursor, src_csr);

  // --- input projection (8-phase GEMM; bf16 out) + LN1 + gelu ---
  gemm8p_kernel<2><<<(N_NODES / 256) * (HID / 256), 512, 0, stream>>>(
      xb, WinT, b_in, b_in, HID, nullptr, cbp, N_NODES, HID, IN_DIM, HID / 256);
  ln_gelu_kernel<<<N_NODES, 256, 0, stream>>>(cbp, ln1g, ln1b, hb);

  // --- GAT layer 1 (fused xl|xr projection, N=2048; wave-per-node tail) ---
  gemm8p_kernel<2><<<(N_NODES / 256) * (XSTR / 256), 512, 0, stream>>>(
      hb, g1WT, g1bl, g1br, HID, nullptr, xe, N_NODES, XSTR, HID, XSTR / 256);
  gat_fused_kernel<0><<<N_NODES / 4, 256, 0, stream>>>(xe, g1att, src_csr, rowstart, g1bo,
                                                       ln2g, ln2b, h, hb);

  // --- GAT layer 2 (writes final fp32 h + bf16 hb) ---
  gemm8p_kernel<2><<<(N_NODES / 256) * (XSTR / 256), 512, 0, stream>>>(
      hb, g2WT, g2bl, g2br, HID, nullptr, xe, N_NODES, XSTR, HID, XSTR / 256);
  gat_fused_kernel<1><<<N_NODES / 4, 256, 0, stream>>>(xe, g2att, src_csr, rowstart, g2bo,
                                                       ln3g, ln3b, h, hb);

  // --- scorer MLP (proven 2-barrier kernel) ---
  gemm_bf16_kernel<1, 2><<<(N_NODES / 256) * (512 / 128), 512, 0, stream>>>(
      hb, Ws1T, bs1, bs1, 512, nullptr, s1b, N_NODES, 512, HID, 512 / 128);
  gemm_bf16_kernel<1, 0><<<(N_NODES / 256) * 1, 512, 0, stream>>>(
      s1b, Ws2T, bs2, bs2, 128, C, nullptr, N_NODES, 128, 512, 1);
  score_kernel<<<N_NODES / 4, 256, 0, stream>>>(C, Ws3, bs3, scores);
}

// Round 17
// 437.864 us; speedup vs baseline: 1.1142x; 1.1142x over previous
//
#include <hip/hip_runtime.h>
#include <hip/hip_bf16.h>
#include <math.h>

#define N_NODES 16384
#define E_EDGES 65536
#define ET (E_EDGES + N_NODES)   /* 81920 edges incl self loops */
#define IN_DIM 1536
#define HID 1024
#define XSTR 2048                /* fused xl|xr row stride */

typedef __attribute__((ext_vector_type(8))) short bf16x8;
typedef __attribute__((ext_vector_type(4))) float f32x4;

__device__ __forceinline__ unsigned short f2b(float f) {
  unsigned int u = __float_as_uint(f);
  u = (u + 0x7FFFu + ((u >> 16) & 1u)) >> 16;
  return (unsigned short)u;
}

__device__ __forceinline__ float b2f(unsigned short u) {
  return __uint_as_float((unsigned int)u << 16);
}

__device__ __forceinline__ void gload_lds16(const void* g, void* l) {
  __builtin_amdgcn_global_load_lds((const __attribute__((address_space(1))) void*)g,
                                   (__attribute__((address_space(3))) void*)l, 16, 0, 0);
}

__device__ __forceinline__ float gelu_exact(float y) {
  return 0.5f * y * (1.0f + erff(y * 0.70710678118654752f));
}

// ---------------------------------------------------------------------------
// fp32 -> bf16 convert (vectorized, streaming roofline)
__global__ void conv_bf16_kernel(const float* __restrict__ in, unsigned short* __restrict__ out, int n4) {
  int i = blockIdx.x * 256 + threadIdx.x;
  if (i < n4) {
    float4 v = ((const float4*)in)[i];
    ushort4 o;
    o.x = f2b(v.x); o.y = f2b(v.y); o.z = f2b(v.z); o.w = f2b(v.w);
    ((ushort4*)out)[i] = o;
  }
}

// ---------------------------------------------------------------------------
// ALL weight transposes fp32 [K][N] -> bf16 [N][K] in ONE launch.
__global__ void transpose_all_kernel(const float* __restrict__ W_in,
                                     const float* __restrict__ g1Wl, const float* __restrict__ g1Wr,
                                     const float* __restrict__ g2Wl, const float* __restrict__ g2Wr,
                                     const float* __restrict__ Ws1, const float* __restrict__ Ws2,
                                     unsigned short* __restrict__ WinT, unsigned short* __restrict__ g1WT,
                                     unsigned short* __restrict__ g2WT, unsigned short* __restrict__ Ws1T,
                                     unsigned short* __restrict__ Ws2T) {
  int bid = blockIdx.x;
  const float* src; unsigned short* dst; int K, N, tile;
  if (bid < 1536)      { src = W_in; dst = WinT;                          K = 1536; N = 1024; tile = bid; }
  else if (bid < 2560) { src = g1Wl; dst = g1WT;                         K = 1024; N = 1024; tile = bid - 1536; }
  else if (bid < 3584) { src = g1Wr; dst = g1WT + (size_t)1024 * 1024;   K = 1024; N = 1024; tile = bid - 2560; }
  else if (bid < 4608) { src = g2Wl; dst = g2WT;                         K = 1024; N = 1024; tile = bid - 3584; }
  else if (bid < 5632) { src = g2Wr; dst = g2WT + (size_t)1024 * 1024;   K = 1024; N = 1024; tile = bid - 4608; }
  else if (bid < 6144) { src = Ws1; dst = Ws1T;                          K = 1024; N = 512;  tile = bid - 5632; }
  else                 { src = Ws2; dst = Ws2T;                          K = 512;  N = 128;  tile = bid - 6144; }
  int nxt = N >> 5;
  int bx = (tile % nxt) * 32;
  int by = (tile / nxt) * 32;
  __shared__ float tilebuf[32][33];
  int tx = threadIdx.x, ty = threadIdx.y;
  #pragma unroll
  for (int i = 0; i < 32; i += 8)
    tilebuf[ty + i][tx] = src[(size_t)(by + ty + i) * N + bx + tx];
  __syncthreads();
  #pragma unroll
  for (int i = 0; i < 32; i += 8)
    dst[(size_t)(bx + ty + i) * K + by + tx] = f2b(tilebuf[tx][ty + i]);
}

// ---------------------------------------------------------------------------
// bf16 MFMA GEMM: C = A*Bt^T + bias; 256x128 tile, BK=64, 8 waves (4x2),
// single-buffer 2-barrier (proven 902 TF structure; 48KB LDS -> 3 blocks/CU,
// cross-block wave overlap hides the barrier drain).
// T2 XOR-swizzle via pre-swizzled global source + T1 XCD chunking.
// Dual bias: col < nsplit -> bias[col], else bias2[col-nsplit].
// ACT: 0 none, 1 silu.  WB: 0 fp32 only, 2 bf16 only.
template <int ACT, int WB>
__global__ __launch_bounds__(512)
void gemm_bf16_kernel(const unsigned short* __restrict__ A, const unsigned short* __restrict__ Bt,
                      const float* __restrict__ bias, const float* __restrict__ bias2, int nsplit,
                      float* __restrict__ C, unsigned short* __restrict__ Cb,
                      int M, int N, int K, int nx) {
  __shared__ unsigned short As[256 * 64];
  __shared__ unsigned short Bs[128 * 64];
  const int t = threadIdx.x;
  const int l = t & 63;
  const int w = t >> 6;            // 0..7
  const int wr = w >> 1, wc = w & 1;

  const int nwg = gridDim.x;
  const int bid = blockIdx.x;
  int tile = bid;
  if ((nwg & 7) == 0) {
    const int cpx = nwg >> 3;
    tile = (bid & 7) * cpx + (bid >> 3);
  }
  const int bm = (tile / nx) * 256;
  const int bn = (tile % nx) * 128;

  f32x4 acc[4][4];
  #pragma unroll
  for (int m = 0; m < 4; m++)
    #pragma unroll
    for (int n = 0; n < 4; n++) acc[m][n] = (f32x4){0.f, 0.f, 0.f, 0.f};

  const int srow = t >> 3;                                  // 0..63
  const int scolbsw = ((t & 7) * 16) ^ ((srow & 7) << 4);   // swizzled byte col
  const unsigned short* Ag = A + (size_t)(bm + srow) * K + (scolbsw >> 1);
  const unsigned short* Bg = Bt + (size_t)(bn + srow) * K + (scolbsw >> 1);

  const int ar = wr * 64 + (l & 15);        // 0..255
  const int br = wc * 64 + (l & 15);        // 0..127
  const int kk2 = (l >> 4) * 16;            // k-fragment byte offset
  const int swA = (ar & 7) << 4;
  const int swB = (br & 7) << 4;
  const char* Asb = (const char*)As;
  const char* Bsb = (const char*)Bs;

  for (int k0 = 0; k0 < K; k0 += 64) {
    #pragma unroll
    for (int i = 0; i < 4; i++)
      gload_lds16(Ag + (size_t)i * 64 * K + k0, (char*)As + t * 16 + i * 8192);
    #pragma unroll
    for (int i = 0; i < 2; i++)
      gload_lds16(Bg + (size_t)i * 64 * K + k0, (char*)Bs + t * 16 + i * 8192);
    __syncthreads();
    bf16x8 af[4], bfr[4];
    #pragma unroll
    for (int kh = 0; kh < 2; kh++) {
      const int kb = kk2 + kh * 64;
      #pragma unroll
      for (int m = 0; m < 4; m++)
        af[m] = *(const bf16x8*)(Asb + (ar + m * 16) * 128 + (kb ^ swA));
      #pragma unroll
      for (int n = 0; n < 4; n++)
        bfr[n] = *(const bf16x8*)(Bsb + (br + n * 16) * 128 + (kb ^ swB));
      #pragma unroll
      for (int m = 0; m < 4; m++)
        #pragma unroll
        for (int n = 0; n < 4; n++)
          acc[m][n] = __builtin_amdgcn_mfma_f32_16x16x32_bf16(af[m], bfr[n], acc[m][n], 0, 0, 0);
    }
    __syncthreads();
  }

  const int crow0 = bm + wr * 64 + (l >> 4) * 4;
  const int ccol0 = bn + wc * 64 + (l & 15);
  #pragma unroll
  for (int m = 0; m < 4; m++) {
    #pragma unroll
    for (int n = 0; n < 4; n++) {
      int col = ccol0 + n * 16;
      float bv = (col < nsplit) ? bias[col] : bias2[col - nsplit];
      #pragma unroll
      for (int v = 0; v < 4; v++) {
        int row = crow0 + m * 16 + v;
        float x = acc[m][n][v] + bv;
        if (ACT == 1) x = x / (1.0f + expf(-x));   // silu
        if (WB != 2) C[(size_t)row * N + col] = x;
        if (WB != 0) Cb[(size_t)row * N + col] = f2b(x);
      }
    }
  }
}

// ---------------------------------------------------------------------------
// layernorm + exact gelu from bf16 input; writes bf16 only (residual chain
// is bf16 until the final layer). Thread t owns channels [4t, 4t+4).
__global__ __launch_bounds__(256)
void ln_gelu_kernel(const unsigned short* __restrict__ cb, const float* __restrict__ g,
                    const float* __restrict__ b, unsigned short* __restrict__ hb) {
  int row = blockIdx.x;
  int t = threadIdx.x;
  int c0 = t * 4;
  ushort4 u = *(const ushort4*)(cb + (size_t)row * HID + c0);
  float v0 = b2f(u.x), v1 = b2f(u.y), v2 = b2f(u.z), v3 = b2f(u.w);
  float s = v0 + v1 + v2 + v3;
  float q = v0 * v0 + v1 * v1 + v2 * v2 + v3 * v3;
  #pragma unroll
  for (int off = 32; off; off >>= 1) {
    s += __shfl_xor(s, off);
    q += __shfl_xor(q, off);
  }
  __shared__ float rs[4], rq[4];
  int wv = t >> 6, l = t & 63;
  if (l == 0) { rs[wv] = s; rq[wv] = q; }
  __syncthreads();
  s = rs[0] + rs[1] + rs[2] + rs[3];
  q = rq[0] + rq[1] + rq[2] + rq[3];
  float mu = s * (1.0f / HID);
  float var = q * (1.0f / HID) - mu * mu;
  float rstd = rsqrtf(var + 1e-5f);
  const float4 gv = *(const float4*)(g + c0);
  const float4 bv = *(const float4*)(b + c0);
  ushort4 ob;
  ob.x = f2b(gelu_exact((v0 - mu) * rstd * gv.x + bv.x));
  ob.y = f2b(gelu_exact((v1 - mu) * rstd * gv.y + bv.y));
  ob.z = f2b(gelu_exact((v2 - mu) * rstd * gv.z + bv.z));
  ob.w = f2b(gelu_exact((v3 - mu) * rstd * gv.w + bv.w));
  *(ushort4*)(hb + (size_t)row * HID + c0) = ob;
}

// ---------------------------------------------------------------------------
// edge list build (+ self loops) and dst-degree histogram
__global__ void build_edges_kernel(const int* __restrict__ ei, int* __restrict__ srcA,
                                   int* __restrict__ dstA, int* __restrict__ deg) {
  int i = blockIdx.x * 256 + threadIdx.x;
  if (i >= ET) return;
  int s, d;
  if (i < E_EDGES) { s = ei[i]; d = ei[E_EDGES + i]; }
  else             { s = i - E_EDGES; d = s; }
  srcA[i] = s;
  dstA[i] = d;
  atomicAdd(&deg[d], 1);
}

// exclusive scan of 16384 degrees, single block of 1024 threads
__global__ __launch_bounds__(1024)
void scan16k_kernel(const int* __restrict__ deg, int* __restrict__ rowstart) {
  __shared__ int s[1024];
  int t = threadIdx.x;
  int local[16];
  int sum = 0;
  #pragma unroll
  for (int i = 0; i < 16; i++) { local[i] = deg[t * 16 + i]; sum += local[i]; }
  s[t] = sum;
  __syncthreads();
  for (int off = 1; off < 1024; off <<= 1) {
    int v = (t >= off) ? s[t - off] : 0;
    __syncthreads();
    s[t] += v;
    __syncthreads();
  }
  int run = s[t] - sum;
  #pragma unroll
  for (int i = 0; i < 16; i++) { rowstart[t * 16 + i] = run; run += local[i]; }
  if (t == 1023) rowstart[16384] = run;
}

// scatter edges into CSR slots; store src per CSR position
__global__ void scatter_edges_kernel(const int* __restrict__ srcA, const int* __restrict__ dstA,
                                     const int* __restrict__ rowstart, int* __restrict__ cursor,
                                     int* __restrict__ src_csr) {
  int i = blockIdx.x * 256 + threadIdx.x;
  if (i >= ET) return;
  int d = dstA[i];
  int pos = atomicAdd(&cursor[d], 1);
  src_csr[rowstart[d] + pos] = srcA[i];
}

// ---------------------------------------------------------------------------
// FUSED GAT layer tail, WAVE-PER-NODE (proven 70us config: one node per wave,
// 64 VGPR, ~31% occupancy): edge logits + online softmax (defer-max) +
// aggregate + bias + LayerNorm + gelu + residual. bf16 residual chain (hb);
// WRITE_H=1 additionally writes the final fp32 h. Lane l owns channels
// [16l, 16l+16). 3-deep edge prefetch; no LDS, no barriers, no conflicts.
template <int WRITE_H>
__global__ __launch_bounds__(256)
void gat_fused_kernel(const unsigned short* __restrict__ xe, const float* __restrict__ att,
                      const int* __restrict__ src_csr, const int* __restrict__ rowstart,
                      const float* __restrict__ bo, const float* __restrict__ lng,
                      const float* __restrict__ lnb, float* __restrict__ h,
                      unsigned short* __restrict__ hb) {
  const int l = threadIdx.x & 63;
  const int nid = blockIdx.x * 4 + (threadIdx.x >> 6);
  const int beg = rowstart[nid], end = rowstart[nid + 1];
  const int cb = l * 16;      // channel base for this lane

  float xrf[16], attf[16];
  {
    const unsigned short* xrd = xe + (size_t)nid * XSTR + 1024 + cb;
    bf16x8 r0 = *(const bf16x8*)xrd;
    bf16x8 r1 = *(const bf16x8*)(xrd + 8);
    #pragma unroll
    for (int j = 0; j < 8; j++) {
      xrf[j] = b2f((unsigned short)r0[j]);
      xrf[j + 8] = b2f((unsigned short)r1[j]);
    }
    #pragma unroll
    for (int j = 0; j < 4; j++) {
      float4 a = *(const float4*)(att + cb + j * 4);
      attf[j * 4] = a.x; attf[j * 4 + 1] = a.y;
      attf[j * 4 + 2] = a.z; attf[j * 4 + 3] = a.w;
    }
  }

  float m = -1e30f, den = 0.f;
  float acc[16];
  #pragma unroll
  for (int j = 0; j < 16; j++) acc[j] = 0.f;

  bf16x8 xa0, xa1, xb0, xb1;
  if (beg < end) {
    const unsigned short* p = xe + (size_t)src_csr[beg] * XSTR + cb;
    xa0 = *(const bf16x8*)p;
    xa1 = *(const bf16x8*)(p + 8);
  }
  if (beg + 1 < end) {
    const unsigned short* p = xe + (size_t)src_csr[beg + 1] * XSTR + cb;
    xb0 = *(const bf16x8*)p;
    xb1 = *(const bf16x8*)(p + 8);
  }
  for (int e = beg; e < end; ++e) {
    bf16x8 c0 = xa0, c1 = xa1;
    xa0 = xb0; xa1 = xb1;
    if (e + 2 < end) {
      const unsigned short* p = xe + (size_t)src_csr[e + 2] * XSTR + cb;
      xb0 = *(const bf16x8*)p;
      xb1 = *(const bf16x8*)(p + 8);
    }
    float xf[16];
    #pragma unroll
    for (int j = 0; j < 8; j++) {
      xf[j] = b2f((unsigned short)c0[j]);
      xf[j + 8] = b2f((unsigned short)c1[j]);
    }
    float lg = 0.f;
    #pragma unroll
    for (int j = 0; j < 16; j++) {
      float u = xf[j] + xrf[j];
      u = fmaxf(u, 0.2f * u);            // leaky_relu (slope<1)
      lg = fmaf(u, attf[j], lg);
    }
    lg += __shfl_xor(lg, 1);
    lg += __shfl_xor(lg, 2);
    lg += __shfl_xor(lg, 4);             // lg = logit of head l>>3
    if (__all(lg <= m + 8.f)) {
      // defer-max fast path: no rescale, weights bounded by e^8
      float wgt = expf(lg - m);
      den += wgt;
      #pragma unroll
      for (int j = 0; j < 16; j++) acc[j] = fmaf(wgt, xf[j], acc[j]);
    } else {
      float nm = fmaxf(m, lg);
      float sc = expf(m - nm);           // first edge: exp(-1e30) == 0
      float wgt = expf(lg - nm);
      den = den * sc + wgt;
      #pragma unroll
      for (int j = 0; j < 16; j++) acc[j] = fmaf(wgt, xf[j], acc[j] * sc);
      m = nm;
    }
  }

  float inv = 1.0f / den;
  float v[16];
  #pragma unroll
  for (int j = 0; j < 4; j++) {
    float4 b = *(const float4*)(bo + cb + j * 4);
    v[j * 4] = acc[j * 4] * inv + b.x;
    v[j * 4 + 1] = acc[j * 4 + 1] * inv + b.y;
    v[j * 4 + 2] = acc[j * 4 + 2] * inv + b.z;
    v[j * 4 + 3] = acc[j * 4 + 3] * inv + b.w;
  }
  // wave-wide LN reduction over 1024 channels
  float s = 0.f, q = 0.f;
  #pragma unroll
  for (int j = 0; j < 16; j++) { s += v[j]; q += v[j] * v[j]; }
  #pragma unroll
  for (int off = 32; off; off >>= 1) {
    s += __shfl_xor(s, off);
    q += __shfl_xor(q, off);
  }
  float mu = s * (1.0f / HID);
  float var = q * (1.0f / HID) - mu * mu;
  float rstd = rsqrtf(var + 1e-5f);

  float* hr = h + (size_t)nid * HID + cb;
  unsigned short* hbr = hb + (size_t)nid * HID + cb;
  #pragma unroll
  for (int j = 0; j < 4; j++) {
    float4 gv = *(const float4*)(lng + cb + j * 4);
    float4 bb = *(const float4*)(lnb + cb + j * 4);
    ushort4 hu = *(const ushort4*)(hbr + j * 4);   // bf16 residual in
    float o0 = b2f(hu.x) + gelu_exact((v[j * 4] - mu) * rstd * gv.x + bb.x);
    float o1 = b2f(hu.y) + gelu_exact((v[j * 4 + 1] - mu) * rstd * gv.y + bb.y);
    float o2 = b2f(hu.z) + gelu_exact((v[j * 4 + 2] - mu) * rstd * gv.z + bb.z);
    float o3 = b2f(hu.w) + gelu_exact((v[j * 4 + 3] - mu) * rstd * gv.w + bb.w);
    if (WRITE_H) *(float4*)(hr + j * 4) = (float4){o0, o1, o2, o3};
    ushort4 ob;
    ob.x = f2b(o0); ob.y = f2b(o1); ob.z = f2b(o2); ob.w = f2b(o3);
    *(ushort4*)(hbr + j * 4) = ob;
  }
}

// final scorer dot: scores[n] = dot(s2[n][0:128], Ws3) + bs3
__global__ __launch_bounds__(256)
void score_kernel(const float* __restrict__ s2, const float* __restrict__ Ws3,
                  const float* __restrict__ bs3, float* __restrict__ out) {
  int nid = blockIdx.x * 4 + (threadIdx.x >> 6);
  int l = threadIdx.x & 63;
  const float* r = s2 + (size_t)nid * 128;
  float a = r[l] * Ws3[l] + r[l + 64] * Ws3[l + 64];
  #pragma unroll
  for (int off = 32; off; off >>= 1) a += __shfl_xor(a, off);
  if (l == 0) out[nid] = a + bs3[0];
}

// ---------------------------------------------------------------------------
extern "C" void kernel_launch(void* const* d_in, const int* in_sizes, int n_in,
                              void* d_out, int out_size, void* d_ws, size_t ws_size,
                              hipStream_t stream) {
  const float* x    = (const float*)d_in[0];
  const int*   ei   = (const int*)  d_in[1];
  const float* W_in = (const float*)d_in[2];
  const float* b_in = (const float*)d_in[3];
  const float* ln1g = (const float*)d_in[4];
  const float* ln1b = (const float*)d_in[5];
  const float* g1Wl = (const float*)d_in[6];
  const float* g1bl = (const float*)d_in[7];
  const float* g1Wr = (const float*)d_in[8];
  const float* g1br = (const float*)d_in[9];
  const float* g1att= (const float*)d_in[10];
  const float* g1bo = (const float*)d_in[11];
  const float* ln2g = (const float*)d_in[12];
  const float* ln2b = (const float*)d_in[13];
  const float* g2Wl = (const float*)d_in[14];
  const float* g2bl = (const float*)d_in[15];
  const float* g2Wr = (const float*)d_in[16];
  const float* g2br = (const float*)d_in[17];
  const float* g2att= (const float*)d_in[18];
  const float* g2bo = (const float*)d_in[19];
  const float* ln3g = (const float*)d_in[20];
  const float* ln3b = (const float*)d_in[21];
  const float* Ws1  = (const float*)d_in[22];
  const float* bs1  = (const float*)d_in[23];
  const float* Ws2  = (const float*)d_in[24];
  const float* bs2  = (const float*)d_in[25];
  const float* Ws3  = (const float*)d_in[26];
  const float* bs3  = (const float*)d_in[27];

  float* scores = (float*)d_out;
  float* h      = (float*)d_out + N_NODES;  // [N][1024] fp32, second output

  char* wsp = (char*)d_ws;
  size_t off = 0;
  auto alloc = [&](size_t bytes) -> char* {
    char* p = wsp + off;
    off += (bytes + 255) & ~(size_t)255;
    return p;
  };
  unsigned short* xb    = (unsigned short*)alloc((size_t)N_NODES * IN_DIM * 2);
  unsigned short* WinT  = (unsigned short*)alloc((size_t)HID * IN_DIM * 2);
  unsigned short* g1WT  = (unsigned short*)alloc((size_t)XSTR * HID * 2);  // [Wl;Wr]^T
  unsigned short* g2WT  = (unsigned short*)alloc((size_t)XSTR * HID * 2);
  unsigned short* Ws1T  = (unsigned short*)alloc((size_t)512 * HID * 2);
  unsigned short* Ws2T  = (unsigned short*)alloc((size_t)128 * 512 * 2);
  unsigned short* hb    = (unsigned short*)alloc((size_t)N_NODES * HID * 2);
  unsigned short* s1b   = (unsigned short*)alloc((size_t)N_NODES * 512 * 2);
  unsigned short* xe    = (unsigned short*)alloc((size_t)N_NODES * XSTR * 2); // fused xl|xr
  float* C      = (float*)alloc((size_t)N_NODES * HID * 4);
  int* srcA     = (int*)alloc((size_t)ET * 4);
  int* dstA     = (int*)alloc((size_t)ET * 4);
  int* deg      = (int*)alloc(65536);
  int* cursor   = (int*)alloc(65536);
  int* rowstart = (int*)alloc(65544);
  int* src_csr  = (int*)alloc((size_t)ET * 4);
  unsigned short* cbp = (unsigned short*)C;   // bf16 proj output aliases C (used before scorer)

  // --- weight/input conversions (batched) ---
  conv_bf16_kernel<<<(N_NODES * IN_DIM / 4 + 255) / 256, 256, 0, stream>>>(x, xb, N_NODES * IN_DIM / 4);
  transpose_all_kernel<<<6208, dim3(32, 8), 0, stream>>>(W_in, g1Wl, g1Wr, g2Wl, g2Wr, Ws1, Ws2,
                                                         WinT, g1WT, g2WT, Ws1T, Ws2T);

  // --- CSR build (shared by both GAT layers) ---
  hipMemsetAsync(deg, 0, 131072, stream);  // deg + cursor (contiguous)
  build_edges_kernel<<<ET / 256, 256, 0, stream>>>(ei, srcA, dstA, deg);
  scan16k_kernel<<<1, 1024, 0, stream>>>(deg, rowstart);
  scatter_edges_kernel<<<ET / 256, 256, 0, stream>>>(srcA, dstA, rowstart, cursor, src_csr);

  // --- input projection (bf16 A via gload_lds; bf16 out) + LN1 + gelu ---
  gemm_bf16_kernel<0, 2><<<(N_NODES / 256) * (HID / 128), 512, 0, stream>>>(
      xb, WinT, b_in, b_in, HID, nullptr, cbp, N_NODES, HID, IN_DIM, HID / 128);
  ln_gelu_kernel<<<N_NODES, 256, 0, stream>>>(cbp, ln1g, ln1b, hb);

  // --- GAT layer 1 (fused xl|xr projection, N=2048; wave-per-node tail) ---
  gemm_bf16_kernel<0, 2><<<(N_NODES / 256) * (XSTR / 128), 512, 0, stream>>>(
      hb, g1WT, g1bl, g1br, HID, nullptr, xe, N_NODES, XSTR, HID, XSTR / 128);
  gat_fused_kernel<0><<<N_NODES / 4, 256, 0, stream>>>(xe, g1att, src_csr, rowstart, g1bo,
                                                       ln2g, ln2b, h, hb);

  // --- GAT layer 2 (writes final fp32 h + bf16 hb) ---
  gemm_bf16_kernel<0, 2><<<(N_NODES / 256) * (XSTR / 128), 512, 0, stream>>>(
      hb, g2WT, g2bl, g2br, HID, nullptr, xe, N_NODES, XSTR, HID, XSTR / 128);
  gat_fused_kernel<1><<<N_NODES / 4, 256, 0, stream>>>(xe, g2att, src_csr, rowstart, g2bo,
                                                       ln3g, ln3b, h, hb);

  // --- scorer MLP ---
  gemm_bf16_kernel<1, 2><<<(N_NODES / 256) * (512 / 128), 512, 0, stream>>>(
      hb, Ws1T, bs1, bs1, 512, nullptr, s1b, N_NODES, 512, HID, 512 / 128);
  gemm_bf16_kernel<1, 0><<<(N_NODES / 256) * 1, 512, 0, stream>>>(
      s1b, Ws2T, bs2, bs2, 128, C, nullptr, N_NODES, 128, 512, 1);
  score_kernel<<<N_NODES / 4, 256, 0, stream>>>(C, Ws3, bs3, scores);
}